// Round 9
// baseline (264.405 us; speedup 1.0000x reference)
//
#include <hip/hip_runtime.h>

#define N_NODES 100000
#define N_EDGES 1600000
#define CAP 60         // per-node bucket capacity, mult. of 12 (Poisson(16): P(deg>60)~1e-16)
#define OVF_CAP 8192
#define GBLK 782       // ceil(100000/128): bin blocks (2048 edges) and k_ag tiles
#define NBIN 1563      // ceil(100000/64): fine bin = dst>>6
#define NCB 98         // ceil(100000/1024): coarse bin = dst>>10
#define CCAP 17408     // Poisson(16384) + 8 sigma
#define BINCAP2 1280   // Poisson(1024) + 8 sigma
#define FBLK 12500     // feat cvt blocks (float4: 3.2M threads)
#define ZROW 100000    // zero row index (padding gathers)

typedef unsigned int uint;
typedef unsigned short ushort;
typedef __attribute__((ext_vector_type(8))) short short8;  // 8 bf16 (4 VGPRs)
typedef __attribute__((ext_vector_type(4))) float f32x4;   // 4 fp32

__device__ __forceinline__ ushort f2bf(float f) {
  uint x = __float_as_uint(f);
  x += 0x7fffu + ((x >> 16) & 1u);  // round-to-nearest-even
  return (ushort)(x >> 16);
}
__device__ __forceinline__ float bflo(uint u) {
  return __uint_as_float(u << 16);
}
__device__ __forceinline__ float bfhi(uint u) {
  return __uint_as_float(u & 0xffff0000u);
}
// low/high 4 floats of a uint4 (8 bf16)
__device__ __forceinline__ f32x4 uplo(uint4 u) {
  return (f32x4){bflo(u.x), bfhi(u.x), bflo(u.y), bfhi(u.y)};
}
__device__ __forceinline__ f32x4 uphi(uint4 u) {
  return (f32x4){bflo(u.z), bfhi(u.z), bflo(u.w), bfhi(u.w)};
}

// ---------------- fused: COARSE edge binning + feat cvt + weight packing ---
// Blocks [0,782): bin 2048 edges into 98 coarse (1024-node) segments.
// Each block's entries per coarse bin get CONSECUTIVE ranks -> ~84B write
// runs. Cursors DENSE (64B-padding measured SLOWER; R6 two-scan also slower).
// Blocks [782,13282): feat f32->bf16 (float4). Then 192 wp blocks + zero rows.
__global__ __launch_bounds__(256) void k_pb(
    const int* __restrict__ src, const int* __restrict__ dst,
    const float* __restrict__ feat, const float* __restrict__ Ws0,
    const float* __restrict__ Wn0, const float* __restrict__ Ws1,
    const float* __restrict__ Wn1, uint* __restrict__ ccur,
    uint* __restrict__ coarse, int* __restrict__ ovf_cnt,
    int* __restrict__ ovf, uint* __restrict__ fbfu, uint* __restrict__ hwu,
    ushort* __restrict__ wp0, ushort* __restrict__ wp1) {
  __shared__ uint hist[NCB];  // counts, then bases (overwritten in place)
  int b = blockIdx.x;
  int tid = threadIdx.x;
  if (b < GBLK) {
    if (tid < NCB) hist[tid] = 0;
    __syncthreads();
    int e0 = b * 2048;
    uint val[8], bn[8], rk[8];
    int vld[8];
#pragma unroll
    for (int it = 0; it < 8; ++it) {
      int e = e0 + it * 256 + tid;
      vld[it] = (e < N_EDGES);
      if (vld[it]) {
        uint s = (uint)src[e];
        uint d = (uint)dst[e];
        bn[it] = d >> 10;
        rk[it] = atomicAdd(&hist[bn[it]], 1u);
        val[it] = s | ((d & 1023u) << 17);  // 27 bits
      }
    }
    __syncthreads();
    if (tid < NCB) {
      uint h = hist[tid];
      hist[tid] = h ? atomicAdd(&ccur[tid], h) : 0u;  // count -> base
    }
    __syncthreads();
#pragma unroll
    for (int it = 0; it < 8; ++it) {
      if (!vld[it]) continue;
      uint p = hist[bn[it]] + rk[it];
      if (p < CCAP) {
        coarse[(size_t)bn[it] * CCAP + p] = val[it];
      } else {  // ~never: segment overflow -> ovf, NOT counted (bit30=0)
        int o = atomicAdd(ovf_cnt, 1);
        if (o < OVF_CAP) {
          ovf[2 * o] = (int)(val[it] & 0x1FFFFu);
          ovf[2 * o + 1] = (int)(bn[it] * 1024 + (val[it] >> 17));
        }
      }
    }
    return;
  }
  if (b < GBLK + FBLK) {  // feat conversion: float4 in, uint2 (4 bf16) out
    int i = (b - GBLK) * 256 + tid;
    float4 v = reinterpret_cast<const float4*>(feat)[i];
    uint2 o;
    o.x = (uint)f2bf(v.x) | ((uint)f2bf(v.y) << 16);
    o.y = (uint)f2bf(v.z) | ((uint)f2bf(v.w) << 16);
    reinterpret_cast<uint2*>(fbfu)[i] = o;
    return;
  }
  int wb = b - GBLK - FBLK;
  if (wb >= 192) {  // zero padding rows fbf[100000], hw[100000]
    if (tid < 64) fbfu[ZROW * 64 + tid] = 0;
    else if (tid < 96) hwu[ZROW * 32 + (tid - 64)] = 0;
    return;
  }
  // B-frag layout (16x16x32 bf16): lane = 16q+c holds B[k=8q+j][n=16t+c].
  int idx = wb * 256 + tid;  // 49152 = 32768 + 16384
  if (idx < 32768) {
    int k = idx >> 7, n = idx & 127;
    float v = (k < 128) ? Ws0[k * 128 + n] : Wn0[(k - 128) * 128 + n];
    int s = k >> 5, q = (k >> 3) & 3, j = k & 7;
    int t = n >> 4, c = n & 15;
    wp0[(((s * 8 + t) * 64) + (q * 16 + c)) * 8 + j] = f2bf(v);
  } else {
    int i2 = idx - 32768;
    int k = i2 >> 7, n = i2 & 127;
    float v = (n < 64) ? Wn1[k * 64 + n] : Ws1[k * 64 + (n - 64)];
    int s = k >> 5, q = (k >> 3) & 3, j = k & 7;
    int t = n >> 4, c = n & 15;
    wp1[(((s * 8 + t) * 64) + (q * 16 + c)) * 8 + j] = f2bf(v);
  }
}

// ---------------- pass B: coarse -> fine binning ---------------------------
// 16 blocks per coarse bin; each scans 1/16 of the segment (coalesced reads)
// and scatters into the coarse bin's 16 fine (64-node) segments.
__global__ __launch_bounds__(256) void k_fb(
    const uint* __restrict__ coarse, const uint* __restrict__ ccur,
    uint* __restrict__ gcursor, int* __restrict__ ovf_cnt,
    int* __restrict__ ovf, uint* __restrict__ binbuf) {
  __shared__ uint hist[16];
  int blk = blockIdx.x;
  int tid = threadIdx.x;
  int cb = blk >> 4, q = blk & 15;
  if (tid < 16) hist[tid] = 0;
  __syncthreads();
  int ne = min((int)ccur[cb], CCAP);
  int lo = (q * ne) >> 4, hi = ((q + 1) * ne) >> 4;  // <= 1088 entries
  uint val[5], rk[5];
  int bnv[5], vld[5];
#pragma unroll
  for (int it = 0; it < 5; ++it) {
    int i = lo + it * 256 + tid;
    vld[it] = (i < hi);
    if (vld[it]) {
      uint v = coarse[(size_t)cb * CCAP + i];
      uint d10 = v >> 17;
      int f = (int)(d10 >> 6);  // 0..15
      rk[it] = atomicAdd(&hist[f], 1u);
      bnv[it] = f;
      val[it] = (v & 0x1FFFFu) | ((d10 & 63u) << 17);
    }
  }
  __syncthreads();
  if (tid < 16) {
    uint h = hist[tid];
    hist[tid] = h ? atomicAdd(&gcursor[cb * 16 + tid], h) : 0u;
  }
  __syncthreads();
#pragma unroll
  for (int it = 0; it < 5; ++it) {
    if (!vld[it]) continue;
    uint p = hist[bnv[it]] + rk[it];
    int fine = cb * 16 + bnv[it];
    if (p < BINCAP2) {
      binbuf[(size_t)fine * BINCAP2 + p] = val[it];
    } else {  // ~never: fine overflow -> ovf, NOT counted (bit30=0)
      int o = atomicAdd(ovf_cnt, 1);
      if (o < OVF_CAP) {
        ovf[2 * o] = (int)(val[it] & 0x1FFFFu);
        ovf[2 * o + 1] = fine * 64 + (int)(val[it] >> 17);
      }
    }
  }
}

// ---------------- FUSED agg0 + gemm0 + gemm1: 1024 threads, 128 rows -------
// Block bb owns nodes [bb*128, bb*128+128) = fine bins {2bb, 2bb+1}.
// A: bucket-scan binbuf into lbkt (aliases htile; ZROW-prefilled).
// B: 12-deep gather from fbf -> mean -> bf16 -> aggt LDS (XOR-swizzled).
// C: GEMM-0 h = relu([fbf | aggt] @ Wp0 + b0) -> htile (lbkt region, dead).
// D: GEMM-1 [hw | out] = htile @ Wp1.
// Saves the 25.6MB agg write + 25.6MB re-read of the split version.
// LDS 64KB -> 2 blocks/CU = 32 waves/CU during gather (R7-measured 3.57TB/s).
__global__ __launch_bounds__(1024, 8) void k_ag(
    const ushort* __restrict__ fbf, const uint4* __restrict__ fbf4,
    const uint* __restrict__ binbuf, const uint* __restrict__ gcursor,
    int* __restrict__ ovf_cnt, int* __restrict__ ovf,
    const short8* __restrict__ wp0f, const short8* __restrict__ wp1f,
    const float* __restrict__ b0, const float* __restrict__ b1,
    ushort* __restrict__ hw, float* __restrict__ out) {
  __shared__ __attribute__((aligned(16))) ushort aggt[128 * 128];   // 32KB
  __shared__ __attribute__((aligned(16))) ushort htile[128 * 128];  // 32KB
  int* lbkt = (int*)htile;                   // [128*CAP] = 30720B
  uint* lcnt = (uint*)(htile + 128 * 120);   // 512B @ byte 30720
  int bb = blockIdx.x;
  int tid = threadIdx.x;
  if (tid < 128) lcnt[tid] = 0;
  for (int i = tid; i < 128 * CAP; i += 1024) lbkt[i] = ZROW;
  __syncthreads();
#pragma unroll
  for (int half = 0; half < 2; ++half) {
    int bin = bb * 2 + half;
    if (bin >= NBIN) break;
    int ne = min((int)gcursor[bin], BINCAP2);
    for (int i = tid; i < ne; i += 1024) {
      uint v = binbuf[(size_t)bin * BINCAP2 + i];
      int ldl = half * 64 + (int)(v >> 17);
      uint pos = atomicAdd(&lcnt[ldl], 1u);
      if (pos < CAP) {
        lbkt[ldl * CAP + pos] = (int)(v & 0x1FFFFu);
      } else {  // ~never: bucket spill -> ovf, already counted (bit30=1)
        int o = atomicAdd(ovf_cnt, 1);
        if (o < OVF_CAP) {
          ovf[2 * o] = (int)(v & 0x1FFFFu);
          ovf[2 * o + 1] = (bb * 128 + ldl) | (1 << 30);
        }
      }
    }
  }
  __syncthreads();
  {  // gather: 2 passes x (64 nodes x 16 lanes)
    int g16 = tid >> 4, li = tid & 15;
    const int4* lb4 = reinterpret_cast<const int4*>(lbkt);
    int oc = min(*ovf_cnt, OVF_CAP);
#pragma unroll
    for (int p = 0; p < 2; ++p) {
      int nl = p * 64 + g16;
      int n = bb * 128 + nl;
      int c = (int)lcnt[nl];
      int kb = min(c, CAP);
      f32x4 accA = (f32x4){0.f, 0.f, 0.f, 0.f};
      f32x4 accB = (f32x4){0.f, 0.f, 0.f, 0.f};
      for (int j = 0; j < kb; j += 12) {
        int4 ia = lb4[nl * 15 + (j >> 2)];
        int4 ib = lb4[nl * 15 + (j >> 2) + 1];
        int4 ic = lb4[nl * 15 + (j >> 2) + 2];
        uint4 u0 = fbf4[(size_t)ia.x * 16 + li];
        uint4 u1 = fbf4[(size_t)ia.y * 16 + li];
        uint4 u2 = fbf4[(size_t)ia.z * 16 + li];
        uint4 u3 = fbf4[(size_t)ia.w * 16 + li];
        uint4 u4 = fbf4[(size_t)ib.x * 16 + li];
        uint4 u5 = fbf4[(size_t)ib.y * 16 + li];
        uint4 u6 = fbf4[(size_t)ib.z * 16 + li];
        uint4 u7 = fbf4[(size_t)ib.w * 16 + li];
        uint4 u8 = fbf4[(size_t)ic.x * 16 + li];
        uint4 u9 = fbf4[(size_t)ic.y * 16 + li];
        uint4 ua = fbf4[(size_t)ic.z * 16 + li];
        uint4 ub = fbf4[(size_t)ic.w * 16 + li];
        accA += uplo(u0); accB += uphi(u0);
        accA += uplo(u1); accB += uphi(u1);
        accA += uplo(u2); accB += uphi(u2);
        accA += uplo(u3); accB += uphi(u3);
        accA += uplo(u4); accB += uphi(u4);
        accA += uplo(u5); accB += uphi(u5);
        accA += uplo(u6); accB += uphi(u6);
        accA += uplo(u7); accB += uphi(u7);
        accA += uplo(u8); accB += uphi(u8);
        accA += uplo(u9); accB += uphi(u9);
        accA += uplo(ua); accB += uphi(ua);
        accA += uplo(ub); accB += uphi(ub);
      }
      for (int i = 0; i < oc; ++i) {  // cold fallback path
        int df = ovf[2 * i + 1];
        if ((df & 0x1FFFF) == n) {
          uint4 u = fbf4[(size_t)ovf[2 * i] * 16 + li];
          accA += uplo(u);
          accB += uphi(u);
          c += ((df >> 30) & 1) ^ 1;
        }
      }
      float inv = 1.f / (float)max(c, 1);
      accA *= inv;
      accB *= inv;
      uint4 o;
      o.x = (uint)f2bf(accA.x) | ((uint)f2bf(accA.y) << 16);
      o.y = (uint)f2bf(accA.z) | ((uint)f2bf(accA.w) << 16);
      o.z = (uint)f2bf(accB.x) | ((uint)f2bf(accB.y) << 16);
      o.w = (uint)f2bf(accB.z) | ((uint)f2bf(accB.w) << 16);
      // swizzled store: cols li*8..li*8+7 of row nl (16B-aligned chunk)
      *reinterpret_cast<uint4*>(&aggt[nl * 128 + ((li * 8) ^ ((nl & 15) * 8))]) = o;
    }
  }
  __syncthreads();  // lbkt dead; htile region reusable

  int lane = tid & 63, w = tid >> 6;  // 16 waves
  int quad = lane >> 4, lm = lane & 15;
  int wr = w >> 2, wc = w & 3;  // wave tile: rows wr*32..+32, cols wc*32..+32
  int rl0 = wr * 32;
  f32x4 acc[2][2];
#pragma unroll
  for (int rt = 0; rt < 2; ++rt)
#pragma unroll
    for (int ct = 0; ct < 2; ++ct) acc[rt][ct] = (f32x4){0.f, 0.f, 0.f, 0.f};
  short8 az = {0, 0, 0, 0, 0, 0, 0, 0};

#pragma unroll
  for (int s = 0; s < 8; ++s) {  // GEMM-0: K=256 over [fbf | aggt]
    int koff = (s & 3) * 32 + quad * 8;
    short8 a[2];
    if (s < 4) {
#pragma unroll
      for (int rt = 0; rt < 2; ++rt) {
        int row = bb * 128 + rl0 + rt * 16 + lm;
        a[rt] = (row < N_NODES)
                    ? *reinterpret_cast<const short8*>(fbf + (size_t)row * 128 + koff)
                    : az;
      }
    } else {
#pragma unroll
      for (int rt = 0; rt < 2; ++rt) {
        int r = rl0 + rt * 16 + lm;
        a[rt] = *reinterpret_cast<const short8*>(
            &aggt[r * 128 + (koff ^ ((r & 15) * 8))]);
      }
    }
#pragma unroll
    for (int ct = 0; ct < 2; ++ct) {
      short8 b = wp0f[(s * 8 + wc * 2 + ct) * 64 + lane];
#pragma unroll
      for (int rt = 0; rt < 2; ++rt)
        acc[rt][ct] =
            __builtin_amdgcn_mfma_f32_16x16x32_bf16(a[rt], b, acc[rt][ct], 0, 0, 0);
    }
  }

  {  // epilogue 0 -> htile (bias + relu + bf16); tail rows zeroed
    float bv[2];
#pragma unroll
    for (int ct = 0; ct < 2; ++ct) bv[ct] = b0[(wc * 2 + ct) * 16 + lm];
#pragma unroll
    for (int rt = 0; rt < 2; ++rt)
#pragma unroll
      for (int ct = 0; ct < 2; ++ct)
#pragma unroll
        for (int i = 0; i < 4; ++i) {
          int r = rl0 + rt * 16 + quad * 4 + i;
          float v = (bb * 128 + r < N_NODES)
                        ? fmaxf(acc[rt][ct][i] + bv[ct], 0.f)
                        : 0.f;
          int col = (wc * 2 + ct) * 16 + lm;
          htile[r * 128 + (col ^ ((r & 15) * 8))] = f2bf(v);
        }
  }
  __syncthreads();

#pragma unroll
  for (int rt = 0; rt < 2; ++rt)
#pragma unroll
    for (int ct = 0; ct < 2; ++ct) acc[rt][ct] = (f32x4){0.f, 0.f, 0.f, 0.f};

#pragma unroll
  for (int s = 0; s < 4; ++s) {  // GEMM-1: K=128 from htile
    int koff = s * 32 + quad * 8;
    short8 a[2];
#pragma unroll
    for (int rt = 0; rt < 2; ++rt) {
      int r = rl0 + rt * 16 + lm;
      a[rt] = *reinterpret_cast<const short8*>(
          &htile[r * 128 + (koff ^ ((r & 15) * 8))]);
    }
#pragma unroll
    for (int ct = 0; ct < 2; ++ct) {
      short8 b = wp1f[(s * 8 + wc * 2 + ct) * 64 + lane];
#pragma unroll
      for (int rt = 0; rt < 2; ++rt)
        acc[rt][ct] =
            __builtin_amdgcn_mfma_f32_16x16x32_bf16(a[rt], b, acc[rt][ct], 0, 0, 0);
    }
  }

  if (wc < 2) {  // cols 0..63 -> hw = h@Wn1 (bf16)
#pragma unroll
    for (int rt = 0; rt < 2; ++rt)
#pragma unroll
      for (int ct = 0; ct < 2; ++ct)
#pragma unroll
        for (int i = 0; i < 4; ++i) {
          int row = bb * 128 + rl0 + rt * 16 + quad * 4 + i;
          if (row < N_NODES)
            hw[(size_t)row * 64 + (wc * 2 + ct) * 16 + lm] = f2bf(acc[rt][ct][i]);
        }
  } else {  // cols 64..127 -> out = h@Ws1 + b1 (f32)
    float bv[2];
#pragma unroll
    for (int ct = 0; ct < 2; ++ct) bv[ct] = b1[((wc - 2) * 2 + ct) * 16 + lm];
#pragma unroll
    for (int rt = 0; rt < 2; ++rt)
#pragma unroll
      for (int ct = 0; ct < 2; ++ct)
#pragma unroll
        for (int i = 0; i < 4; ++i) {
          int row = bb * 128 + rl0 + rt * 16 + quad * 4 + i;
          if (row < N_NODES)
            out[(size_t)row * 64 + ((wc - 2) * 2 + ct) * 16 + lm] =
                acc[rt][ct][i] + bv[ct];
        }
  }
}

// ---------------- layer-1 aggregation: 512 threads, 64 nodes/block ---------
// Same bin geometry as before (1563 blocks); 64 nodes x 8 lanes = 512,
// single pass. 4 blocks/CU (thread-capped) = 32 waves/CU vs 24.4 at 256thr:
// the R7 agg0 maneuver (raised random-fetch rate 3.3 -> 3.57 TB/s) without
// R7's bin-geometry traffic growth.
__global__ __launch_bounds__(512, 8) void k_agg1(
    const uint4* __restrict__ hw4, const uint* __restrict__ binbuf,
    const uint* __restrict__ gcursor, int* __restrict__ ovf_cnt,
    int* __restrict__ ovf, float* __restrict__ out) {
  __shared__ __attribute__((aligned(16))) int lbkt[64 * CAP];
  __shared__ uint lcnt[64];
  int bb = blockIdx.x;
  int tid = threadIdx.x;
  if (tid < 64) lcnt[tid] = 0;
  for (int i = tid; i < 64 * CAP; i += 512) lbkt[i] = ZROW;
  __syncthreads();
  int ne = min((int)gcursor[bb], BINCAP2);
  for (int i = tid; i < ne; i += 512) {
    uint v = binbuf[(size_t)bb * BINCAP2 + i];
    int ldl = (int)(v >> 17);
    uint pos = atomicAdd(&lcnt[ldl], 1u);
    if (pos < CAP) lbkt[ldl * CAP + pos] = (int)(v & 0x1FFFFu);
    // bucket spill already recorded in ovf by k_ag's pass (bit30=1)
  }
  __syncthreads();
  int g = tid >> 3, li = tid & 7;  // g in [0,64): one node per 8 lanes
  const int4* lb4 = reinterpret_cast<const int4*>(lbkt);
  int oc = min(*ovf_cnt, OVF_CAP);
  int n = bb * 64 + g;
  int c = (int)lcnt[g];
  int kb = min(c, CAP);
  f32x4 accA = (f32x4){0.f, 0.f, 0.f, 0.f};
  f32x4 accB = (f32x4){0.f, 0.f, 0.f, 0.f};
  for (int j = 0; j < kb; j += 12) {
    int4 ia = lb4[g * 15 + (j >> 2)];
    int4 ib = lb4[g * 15 + (j >> 2) + 1];
    int4 ic = lb4[g * 15 + (j >> 2) + 2];
    uint4 u0 = hw4[(size_t)ia.x * 8 + li];
    uint4 u1 = hw4[(size_t)ia.y * 8 + li];
    uint4 u2 = hw4[(size_t)ia.z * 8 + li];
    uint4 u3 = hw4[(size_t)ia.w * 8 + li];
    uint4 u4 = hw4[(size_t)ib.x * 8 + li];
    uint4 u5 = hw4[(size_t)ib.y * 8 + li];
    uint4 u6 = hw4[(size_t)ib.z * 8 + li];
    uint4 u7 = hw4[(size_t)ib.w * 8 + li];
    uint4 u8 = hw4[(size_t)ic.x * 8 + li];
    uint4 u9 = hw4[(size_t)ic.y * 8 + li];
    uint4 ua = hw4[(size_t)ic.z * 8 + li];
    uint4 ub = hw4[(size_t)ic.w * 8 + li];
    accA += uplo(u0); accB += uphi(u0);
    accA += uplo(u1); accB += uphi(u1);
    accA += uplo(u2); accB += uphi(u2);
    accA += uplo(u3); accB += uphi(u3);
    accA += uplo(u4); accB += uphi(u4);
    accA += uplo(u5); accB += uphi(u5);
    accA += uplo(u6); accB += uphi(u6);
    accA += uplo(u7); accB += uphi(u7);
    accA += uplo(u8); accB += uphi(u8);
    accA += uplo(u9); accB += uphi(u9);
    accA += uplo(ua); accB += uphi(ua);
    accA += uplo(ub); accB += uphi(ub);
  }
  for (int i = 0; i < oc; ++i) {  // cold fallback path
    int df = ovf[2 * i + 1];
    if ((df & 0x1FFFF) == n) {
      uint4 u = hw4[(size_t)ovf[2 * i] * 8 + li];
      accA += uplo(u);
      accB += uphi(u);
      c += ((df >> 30) & 1) ^ 1;
    }
  }
  if (n < N_NODES) {
    float inv = 1.f / (float)max(c, 1);
    float* op = out + (size_t)n * 64 + li * 8;
    float4 c0 = *reinterpret_cast<float4*>(op);
    float4 c1 = *reinterpret_cast<float4*>(op + 4);
    c0.x += accA.x * inv;
    c0.y += accA.y * inv;
    c0.z += accA.z * inv;
    c0.w += accA.w * inv;
    c1.x += accB.x * inv;
    c1.y += accB.y * inv;
    c1.z += accB.z * inv;
    c1.w += accB.w * inv;
    *reinterpret_cast<float4*>(op) = c0;
    *reinterpret_cast<float4*>(op + 4) = c1;
  }
}

extern "C" void kernel_launch(void* const* d_in, const int* in_sizes, int n_in,
                              void* d_out, int out_size, void* d_ws,
                              size_t ws_size, hipStream_t stream) {
  const float* feat = (const float*)d_in[0];
  const int* src = (const int*)d_in[1];
  const int* dst = (const int*)d_in[2];
  const float* Ws0 = (const float*)d_in[3];
  const float* Wn0 = (const float*)d_in[4];
  const float* b0 = (const float*)d_in[5];
  const float* Ws1 = (const float*)d_in[6];
  const float* Wn1 = (const float*)d_in[7];
  const float* b1 = (const float*)d_in[8];
  char* ws = (char*)d_ws;

  // Workspace (72.2 MB <= 77.2 MB proven):
  //   coarse  @ 0          : 25,600,000  (coarse binbuf; k_pb/k_fb only)
  //   ovf_cnt @ 25,600,000 :         64
  //   gcursor @ 25,600,064 :      6,272  (1568 fine cursors, dense)
  //   ccur    @ 25,606,336 :        448  (98 coarse cursors, dense)
  //   ovf     @ 25,606,784 :     65,536
  //   binbuf  @ 25,672,320 :  8,002,560  (1563 x 1280 packed edges)
  //   feat_bf @ 33,674,880 : 25,600,256  (bf16 + zero row)
  //   hw      @ 59,275,136 : 12,800,128  (bf16 h@Wn1 + zero row)
  //   wp0     @ 72,075,264 :     65,536
  //   wp1     @ 72,140,800 :     32,768
  uint* coarse = (uint*)(ws);
  int* ovf_cnt = (int*)(ws + 25600000);
  uint* gcursor = (uint*)(ws + 25600064);
  uint* ccur = (uint*)(ws + 25606336);
  int* ovf = (int*)(ws + 25606784);
  uint* binbuf = (uint*)(ws + 25672320);
  ushort* fbf = (ushort*)(ws + 33674880);
  ushort* hw = (ushort*)(ws + 59275136);
  ushort* wp0 = (ushort*)(ws + 72075264);
  ushort* wp1 = (ushort*)(ws + 72140800);
  float* out = (float*)d_out;

  hipMemsetAsync(ws + 25600000, 0, 6784, stream);  // ovf_cnt+gcursor+ccur
  k_pb<<<GBLK + FBLK + 193, 256, 0, stream>>>(
      src, dst, feat, Ws0, Wn0, Ws1, Wn1, ccur, coarse, ovf_cnt, ovf,
      (uint*)fbf, (uint*)hw, wp0, wp1);
  k_fb<<<NCB * 16, 256, 0, stream>>>(coarse, ccur, gcursor, ovf_cnt, ovf,
                                     binbuf);
  k_ag<<<GBLK, 1024, 0, stream>>>(fbf, (const uint4*)fbf, binbuf, gcursor,
                                  ovf_cnt, ovf, (const short8*)wp0,
                                  (const short8*)wp1, b0, b1, hw, out);
  k_agg1<<<NBIN, 512, 0, stream>>>((const uint4*)hw, binbuf, gcursor, ovf_cnt,
                                   ovf, out);
}

// Round 10
// 256.293 us; speedup vs baseline: 1.0317x; 1.0317x over previous
//
#include <hip/hip_runtime.h>

#define N_NODES 100000
#define N_EDGES 1600000
#define CAP 60         // per-node bucket capacity, mult. of 12 (Poisson(16): P(deg>60)~1e-16)
#define OVF_CAP 8192
#define GBLK 782       // ceil(100000/128): bin blocks (2048 edges)
#define NBIN 1563      // ceil(100000/64): fine bin = dst>>6; k_ag/k_agg1 grid
#define NCB 98         // ceil(100000/1024): coarse bin = dst>>10
#define CCAP 17408     // Poisson(16384) + 8 sigma
#define BINCAP2 1280   // Poisson(1024) + 8 sigma
#define FBLK 12500     // feat cvt blocks (float4: 3.2M threads)
#define ZROW 100000    // zero row index (padding gathers)

typedef unsigned int uint;
typedef unsigned short ushort;
typedef __attribute__((ext_vector_type(8))) short short8;  // 8 bf16 (4 VGPRs)
typedef __attribute__((ext_vector_type(4))) float f32x4;   // 4 fp32

__device__ __forceinline__ ushort f2bf(float f) {
  uint x = __float_as_uint(f);
  x += 0x7fffu + ((x >> 16) & 1u);  // round-to-nearest-even
  return (ushort)(x >> 16);
}
__device__ __forceinline__ float bflo(uint u) {
  return __uint_as_float(u << 16);
}
__device__ __forceinline__ float bfhi(uint u) {
  return __uint_as_float(u & 0xffff0000u);
}
// low/high 4 floats of a uint4 (8 bf16)
__device__ __forceinline__ f32x4 uplo(uint4 u) {
  return (f32x4){bflo(u.x), bfhi(u.x), bflo(u.y), bfhi(u.y)};
}
__device__ __forceinline__ f32x4 uphi(uint4 u) {
  return (f32x4){bflo(u.z), bfhi(u.z), bflo(u.w), bfhi(u.w)};
}

// ---------------- fused: COARSE edge binning + feat cvt + weight packing ---
// Blocks [0,782): bin 2048 edges into 98 coarse (1024-node) segments.
// Each block's entries per coarse bin get CONSECUTIVE ranks -> ~84B write
// runs. Cursors DENSE (64B-padding measured SLOWER; R6 two-scan also slower).
// Blocks [782,13282): feat f32->bf16 (float4). Then 192 wp blocks + zero rows.
__global__ __launch_bounds__(256) void k_pb(
    const int* __restrict__ src, const int* __restrict__ dst,
    const float* __restrict__ feat, const float* __restrict__ Ws0,
    const float* __restrict__ Wn0, const float* __restrict__ Ws1,
    const float* __restrict__ Wn1, uint* __restrict__ ccur,
    uint* __restrict__ coarse, int* __restrict__ ovf_cnt,
    int* __restrict__ ovf, uint* __restrict__ fbfu, uint* __restrict__ hwu,
    ushort* __restrict__ wp0, ushort* __restrict__ wp1) {
  __shared__ uint hist[NCB];  // counts, then bases (overwritten in place)
  int b = blockIdx.x;
  int tid = threadIdx.x;
  if (b < GBLK) {
    if (tid < NCB) hist[tid] = 0;
    __syncthreads();
    int e0 = b * 2048;
    uint val[8], bn[8], rk[8];
    int vld[8];
#pragma unroll
    for (int it = 0; it < 8; ++it) {
      int e = e0 + it * 256 + tid;
      vld[it] = (e < N_EDGES);
      if (vld[it]) {
        uint s = (uint)src[e];
        uint d = (uint)dst[e];
        bn[it] = d >> 10;
        rk[it] = atomicAdd(&hist[bn[it]], 1u);
        val[it] = s | ((d & 1023u) << 17);  // 27 bits
      }
    }
    __syncthreads();
    if (tid < NCB) {
      uint h = hist[tid];
      hist[tid] = h ? atomicAdd(&ccur[tid], h) : 0u;  // count -> base
    }
    __syncthreads();
#pragma unroll
    for (int it = 0; it < 8; ++it) {
      if (!vld[it]) continue;
      uint p = hist[bn[it]] + rk[it];
      if (p < CCAP) {
        coarse[(size_t)bn[it] * CCAP + p] = val[it];
      } else {  // ~never: segment overflow -> ovf, NOT counted (bit30=0)
        int o = atomicAdd(ovf_cnt, 1);
        if (o < OVF_CAP) {
          ovf[2 * o] = (int)(val[it] & 0x1FFFFu);
          ovf[2 * o + 1] = (int)(bn[it] * 1024 + (val[it] >> 17));
        }
      }
    }
    return;
  }
  if (b < GBLK + FBLK) {  // feat conversion: float4 in, uint2 (4 bf16) out
    int i = (b - GBLK) * 256 + tid;
    float4 v = reinterpret_cast<const float4*>(feat)[i];
    uint2 o;
    o.x = (uint)f2bf(v.x) | ((uint)f2bf(v.y) << 16);
    o.y = (uint)f2bf(v.z) | ((uint)f2bf(v.w) << 16);
    reinterpret_cast<uint2*>(fbfu)[i] = o;
    return;
  }
  int wb = b - GBLK - FBLK;
  if (wb >= 192) {  // zero padding rows fbf[100000], hw[100000]
    if (tid < 64) fbfu[ZROW * 64 + tid] = 0;
    else if (tid < 96) hwu[ZROW * 32 + (tid - 64)] = 0;
    return;
  }
  // B-frag layout (16x16x32 bf16): lane = 16q+c holds B[k=8q+j][n=16t+c].
  int idx = wb * 256 + tid;  // 49152 = 32768 + 16384
  if (idx < 32768) {
    int k = idx >> 7, n = idx & 127;
    float v = (k < 128) ? Ws0[k * 128 + n] : Wn0[(k - 128) * 128 + n];
    int s = k >> 5, q = (k >> 3) & 3, j = k & 7;
    int t = n >> 4, c = n & 15;
    wp0[(((s * 8 + t) * 64) + (q * 16 + c)) * 8 + j] = f2bf(v);
  } else {
    int i2 = idx - 32768;
    int k = i2 >> 7, n = i2 & 127;
    float v = (n < 64) ? Wn1[k * 64 + n] : Ws1[k * 64 + (n - 64)];
    int s = k >> 5, q = (k >> 3) & 3, j = k & 7;
    int t = n >> 4, c = n & 15;
    wp1[(((s * 8 + t) * 64) + (q * 16 + c)) * 8 + j] = f2bf(v);
  }
}

// ---------------- pass B: coarse -> fine binning ---------------------------
// 16 blocks per coarse bin; each scans 1/16 of the segment (coalesced reads)
// and scatters into the coarse bin's 16 fine (64-node) segments.
__global__ __launch_bounds__(256) void k_fb(
    const uint* __restrict__ coarse, const uint* __restrict__ ccur,
    uint* __restrict__ gcursor, int* __restrict__ ovf_cnt,
    int* __restrict__ ovf, uint* __restrict__ binbuf) {
  __shared__ uint hist[16];
  int blk = blockIdx.x;
  int tid = threadIdx.x;
  int cb = blk >> 4, q = blk & 15;
  if (tid < 16) hist[tid] = 0;
  __syncthreads();
  int ne = min((int)ccur[cb], CCAP);
  int lo = (q * ne) >> 4, hi = ((q + 1) * ne) >> 4;  // <= 1088 entries
  uint val[5], rk[5];
  int bnv[5], vld[5];
#pragma unroll
  for (int it = 0; it < 5; ++it) {
    int i = lo + it * 256 + tid;
    vld[it] = (i < hi);
    if (vld[it]) {
      uint v = coarse[(size_t)cb * CCAP + i];
      uint d10 = v >> 17;
      int f = (int)(d10 >> 6);  // 0..15
      rk[it] = atomicAdd(&hist[f], 1u);
      bnv[it] = f;
      val[it] = (v & 0x1FFFFu) | ((d10 & 63u) << 17);
    }
  }
  __syncthreads();
  if (tid < 16) {
    uint h = hist[tid];
    hist[tid] = h ? atomicAdd(&gcursor[cb * 16 + tid], h) : 0u;
  }
  __syncthreads();
#pragma unroll
  for (int it = 0; it < 5; ++it) {
    if (!vld[it]) continue;
    uint p = hist[bnv[it]] + rk[it];
    int fine = cb * 16 + bnv[it];
    if (p < BINCAP2) {
      binbuf[(size_t)fine * BINCAP2 + p] = val[it];
    } else {  // ~never: fine overflow -> ovf, NOT counted (bit30=0)
      int o = atomicAdd(ovf_cnt, 1);
      if (o < OVF_CAP) {
        ovf[2 * o] = (int)(val[it] & 0x1FFFFu);
        ovf[2 * o + 1] = fine * 64 + (int)(val[it] >> 17);
      }
    }
  }
}

// ---------------- FUSED agg0 + gemm0 + gemm1: 512 threads, 64 rows ---------
// Block bb owns nodes [bb*64, bb*64+64) = fine bin bb.
// A: bucket-scan binbuf into lbkt (aliases htile; ZROW-prefilled).
// B: 12-deep gather from fbf -> mean -> bf16 -> aggt LDS (XOR-swizzled).
// C: GEMM-0 h = relu([fbf | aggt] @ Wp0 + b0) -> htile (lbkt region, dead).
// D: GEMM-1 [hw | out] = htile @ Wp1.
// 64-row blocks (vs 128): LDS 32KB -> 4 resident blocks/CU. Independently
// phased blocks let gather-fetch overlap GEMM-MFMA across blocks (the R8
// 2-block config phase-aligned: 2.8 TB/s vs 3.57 standalone).
__global__ __launch_bounds__(512, 8) void k_ag(
    const ushort* __restrict__ fbf, const uint4* __restrict__ fbf4,
    const uint* __restrict__ binbuf, const uint* __restrict__ gcursor,
    int* __restrict__ ovf_cnt, int* __restrict__ ovf,
    const short8* __restrict__ wp0f, const short8* __restrict__ wp1f,
    const float* __restrict__ b0, const float* __restrict__ b1,
    ushort* __restrict__ hw, float* __restrict__ out) {
  __shared__ __attribute__((aligned(16))) ushort aggt[64 * 128];   // 16KB
  __shared__ __attribute__((aligned(16))) ushort htile[64 * 128];  // 16KB
  int* lbkt = (int*)htile;                  // [64*CAP] = 15360B
  uint* lcnt = (uint*)(htile + 7680);       // 256B @ byte 15360
  int bb = blockIdx.x;
  int tid = threadIdx.x;
  if (tid < 64) lcnt[tid] = 0;
  for (int i = tid; i < 64 * CAP; i += 512) lbkt[i] = ZROW;
  __syncthreads();
  int ne = min((int)gcursor[bb], BINCAP2);
  for (int i = tid; i < ne; i += 512) {
    uint v = binbuf[(size_t)bb * BINCAP2 + i];
    int ldl = (int)(v >> 17);
    uint pos = atomicAdd(&lcnt[ldl], 1u);
    if (pos < CAP) {
      lbkt[ldl * CAP + pos] = (int)(v & 0x1FFFFu);
    } else {  // ~never: bucket spill -> ovf, already counted (bit30=1)
      int o = atomicAdd(ovf_cnt, 1);
      if (o < OVF_CAP) {
        ovf[2 * o] = (int)(v & 0x1FFFFu);
        ovf[2 * o + 1] = (bb * 64 + ldl) | (1 << 30);
      }
    }
  }
  __syncthreads();
  {  // gather: 2 passes x (32 nodes x 16 lanes)
    int g16 = tid >> 4, li = tid & 15;
    const int4* lb4 = reinterpret_cast<const int4*>(lbkt);
    int oc = min(*ovf_cnt, OVF_CAP);
#pragma unroll
    for (int p = 0; p < 2; ++p) {
      int nl = p * 32 + g16;
      int n = bb * 64 + nl;
      int c = (int)lcnt[nl];
      int kb = min(c, CAP);
      f32x4 accA = (f32x4){0.f, 0.f, 0.f, 0.f};
      f32x4 accB = (f32x4){0.f, 0.f, 0.f, 0.f};
      for (int j = 0; j < kb; j += 12) {
        int4 ia = lb4[nl * 15 + (j >> 2)];
        int4 ib = lb4[nl * 15 + (j >> 2) + 1];
        int4 ic = lb4[nl * 15 + (j >> 2) + 2];
        uint4 u0 = fbf4[(size_t)ia.x * 16 + li];
        uint4 u1 = fbf4[(size_t)ia.y * 16 + li];
        uint4 u2 = fbf4[(size_t)ia.z * 16 + li];
        uint4 u3 = fbf4[(size_t)ia.w * 16 + li];
        uint4 u4 = fbf4[(size_t)ib.x * 16 + li];
        uint4 u5 = fbf4[(size_t)ib.y * 16 + li];
        uint4 u6 = fbf4[(size_t)ib.z * 16 + li];
        uint4 u7 = fbf4[(size_t)ib.w * 16 + li];
        uint4 u8 = fbf4[(size_t)ic.x * 16 + li];
        uint4 u9 = fbf4[(size_t)ic.y * 16 + li];
        uint4 ua = fbf4[(size_t)ic.z * 16 + li];
        uint4 ub = fbf4[(size_t)ic.w * 16 + li];
        accA += uplo(u0); accB += uphi(u0);
        accA += uplo(u1); accB += uphi(u1);
        accA += uplo(u2); accB += uphi(u2);
        accA += uplo(u3); accB += uphi(u3);
        accA += uplo(u4); accB += uphi(u4);
        accA += uplo(u5); accB += uphi(u5);
        accA += uplo(u6); accB += uphi(u6);
        accA += uplo(u7); accB += uphi(u7);
        accA += uplo(u8); accB += uphi(u8);
        accA += uplo(u9); accB += uphi(u9);
        accA += uplo(ua); accB += uphi(ua);
        accA += uplo(ub); accB += uphi(ub);
      }
      for (int i = 0; i < oc; ++i) {  // cold fallback path
        int df = ovf[2 * i + 1];
        if ((df & 0x1FFFF) == n) {
          uint4 u = fbf4[(size_t)ovf[2 * i] * 16 + li];
          accA += uplo(u);
          accB += uphi(u);
          c += ((df >> 30) & 1) ^ 1;
        }
      }
      float inv = 1.f / (float)max(c, 1);
      accA *= inv;
      accB *= inv;
      uint4 o;
      o.x = (uint)f2bf(accA.x) | ((uint)f2bf(accA.y) << 16);
      o.y = (uint)f2bf(accA.z) | ((uint)f2bf(accA.w) << 16);
      o.z = (uint)f2bf(accB.x) | ((uint)f2bf(accB.y) << 16);
      o.w = (uint)f2bf(accB.z) | ((uint)f2bf(accB.w) << 16);
      // swizzled store: cols li*8..li*8+7 of row nl (16B-aligned chunk)
      *reinterpret_cast<uint4*>(&aggt[nl * 128 + ((li * 8) ^ ((nl & 15) * 8))]) = o;
    }
  }
  __syncthreads();  // lbkt dead; htile region reusable

  int lane = tid & 63, w = tid >> 6;  // 8 waves
  int quad = lane >> 4, lm = lane & 15;
  int wr = w >> 2, wc = w & 3;  // wave tile: rows wr*32..+32, cols wc*32..+32
  int rl0 = wr * 32;
  f32x4 acc[2][2];
#pragma unroll
  for (int rt = 0; rt < 2; ++rt)
#pragma unroll
    for (int ct = 0; ct < 2; ++ct) acc[rt][ct] = (f32x4){0.f, 0.f, 0.f, 0.f};
  short8 az = {0, 0, 0, 0, 0, 0, 0, 0};

#pragma unroll
  for (int s = 0; s < 8; ++s) {  // GEMM-0: K=256 over [fbf | aggt]
    int koff = (s & 3) * 32 + quad * 8;
    short8 a[2];
    if (s < 4) {
#pragma unroll
      for (int rt = 0; rt < 2; ++rt) {
        int row = bb * 64 + rl0 + rt * 16 + lm;
        a[rt] = (row < N_NODES)
                    ? *reinterpret_cast<const short8*>(fbf + (size_t)row * 128 + koff)
                    : az;
      }
    } else {
#pragma unroll
      for (int rt = 0; rt < 2; ++rt) {
        int r = rl0 + rt * 16 + lm;
        a[rt] = *reinterpret_cast<const short8*>(
            &aggt[r * 128 + (koff ^ ((r & 15) * 8))]);
      }
    }
#pragma unroll
    for (int ct = 0; ct < 2; ++ct) {
      short8 b = wp0f[(s * 8 + wc * 2 + ct) * 64 + lane];
#pragma unroll
      for (int rt = 0; rt < 2; ++rt)
        acc[rt][ct] =
            __builtin_amdgcn_mfma_f32_16x16x32_bf16(a[rt], b, acc[rt][ct], 0, 0, 0);
    }
  }

  {  // epilogue 0 -> htile (bias + relu + bf16); tail rows zeroed
    float bv[2];
#pragma unroll
    for (int ct = 0; ct < 2; ++ct) bv[ct] = b0[(wc * 2 + ct) * 16 + lm];
#pragma unroll
    for (int rt = 0; rt < 2; ++rt)
#pragma unroll
      for (int ct = 0; ct < 2; ++ct)
#pragma unroll
        for (int i = 0; i < 4; ++i) {
          int r = rl0 + rt * 16 + quad * 4 + i;
          float v = (bb * 64 + r < N_NODES)
                        ? fmaxf(acc[rt][ct][i] + bv[ct], 0.f)
                        : 0.f;
          int col = (wc * 2 + ct) * 16 + lm;
          htile[r * 128 + (col ^ ((r & 15) * 8))] = f2bf(v);
        }
  }
  __syncthreads();

#pragma unroll
  for (int rt = 0; rt < 2; ++rt)
#pragma unroll
    for (int ct = 0; ct < 2; ++ct) acc[rt][ct] = (f32x4){0.f, 0.f, 0.f, 0.f};

#pragma unroll
  for (int s = 0; s < 4; ++s) {  // GEMM-1: K=128 from htile
    int koff = s * 32 + quad * 8;
    short8 a[2];
#pragma unroll
    for (int rt = 0; rt < 2; ++rt) {
      int r = rl0 + rt * 16 + lm;
      a[rt] = *reinterpret_cast<const short8*>(
          &htile[r * 128 + (koff ^ ((r & 15) * 8))]);
    }
#pragma unroll
    for (int ct = 0; ct < 2; ++ct) {
      short8 b = wp1f[(s * 8 + wc * 2 + ct) * 64 + lane];
#pragma unroll
      for (int rt = 0; rt < 2; ++rt)
        acc[rt][ct] =
            __builtin_amdgcn_mfma_f32_16x16x32_bf16(a[rt], b, acc[rt][ct], 0, 0, 0);
    }
  }

  if (wc < 2) {  // cols 0..63 -> hw = h@Wn1 (bf16)
#pragma unroll
    for (int rt = 0; rt < 2; ++rt)
#pragma unroll
      for (int ct = 0; ct < 2; ++ct)
#pragma unroll
        for (int i = 0; i < 4; ++i) {
          int row = bb * 64 + rl0 + rt * 16 + quad * 4 + i;
          if (row < N_NODES)
            hw[(size_t)row * 64 + (wc * 2 + ct) * 16 + lm] = f2bf(acc[rt][ct][i]);
        }
  } else {  // cols 64..127 -> out = h@Ws1 + b1 (f32)
    float bv[2];
#pragma unroll
    for (int ct = 0; ct < 2; ++ct) bv[ct] = b1[((wc - 2) * 2 + ct) * 16 + lm];
#pragma unroll
    for (int rt = 0; rt < 2; ++rt)
#pragma unroll
      for (int ct = 0; ct < 2; ++ct)
#pragma unroll
        for (int i = 0; i < 4; ++i) {
          int row = bb * 64 + rl0 + rt * 16 + quad * 4 + i;
          if (row < N_NODES)
            out[(size_t)row * 64 + ((wc - 2) * 2 + ct) * 16 + lm] =
                acc[rt][ct][i] + bv[ct];
        }
  }
}

// ---------------- layer-1 aggregation (LDS bucket): 64 nodes/block ---------
// R8 structure (best measured): 256 threads, 8 lanes per node, 12-deep.
__global__ __launch_bounds__(256) void k_agg1(
    const uint4* __restrict__ hw4, const uint* __restrict__ binbuf,
    const uint* __restrict__ gcursor, int* __restrict__ ovf_cnt,
    int* __restrict__ ovf, float* __restrict__ out) {
  __shared__ __attribute__((aligned(16))) int lbkt[64 * CAP];
  __shared__ uint lcnt[64];
  int bb = blockIdx.x;
  int tid = threadIdx.x;
  if (tid < 64) lcnt[tid] = 0;
#pragma unroll
  for (int i = tid; i < 64 * CAP; i += 256) lbkt[i] = ZROW;
  __syncthreads();
  int ne = min((int)gcursor[bb], BINCAP2);
  for (int i = tid; i < ne; i += 256) {
    uint v = binbuf[(size_t)bb * BINCAP2 + i];
    int ldl = (int)(v >> 17);
    uint pos = atomicAdd(&lcnt[ldl], 1u);
    if (pos < CAP) lbkt[ldl * CAP + pos] = (int)(v & 0x1FFFFu);
    // bucket spill already recorded in ovf by k_ag's pass (bit30=1)
  }
  __syncthreads();
  int g = tid >> 3, li = tid & 7;
  const int4* lb4 = reinterpret_cast<const int4*>(lbkt);
  int oc = min(*ovf_cnt, OVF_CAP);
#pragma unroll
  for (int p = 0; p < 2; ++p) {
    int nl = p * 32 + g;
    int n = bb * 64 + nl;
    int c = (int)lcnt[nl];
    int kb = min(c, CAP);
    f32x4 accA = (f32x4){0.f, 0.f, 0.f, 0.f};
    f32x4 accB = (f32x4){0.f, 0.f, 0.f, 0.f};
    for (int j = 0; j < kb; j += 12) {
      int4 ia = lb4[nl * 15 + (j >> 2)];
      int4 ib = lb4[nl * 15 + (j >> 2) + 1];
      int4 ic = lb4[nl * 15 + (j >> 2) + 2];
      uint4 u0 = hw4[(size_t)ia.x * 8 + li];
      uint4 u1 = hw4[(size_t)ia.y * 8 + li];
      uint4 u2 = hw4[(size_t)ia.z * 8 + li];
      uint4 u3 = hw4[(size_t)ia.w * 8 + li];
      uint4 u4 = hw4[(size_t)ib.x * 8 + li];
      uint4 u5 = hw4[(size_t)ib.y * 8 + li];
      uint4 u6 = hw4[(size_t)ib.z * 8 + li];
      uint4 u7 = hw4[(size_t)ib.w * 8 + li];
      uint4 u8 = hw4[(size_t)ic.x * 8 + li];
      uint4 u9 = hw4[(size_t)ic.y * 8 + li];
      uint4 ua = hw4[(size_t)ic.z * 8 + li];
      uint4 ub = hw4[(size_t)ic.w * 8 + li];
      accA += uplo(u0); accB += uphi(u0);
      accA += uplo(u1); accB += uphi(u1);
      accA += uplo(u2); accB += uphi(u2);
      accA += uplo(u3); accB += uphi(u3);
      accA += uplo(u4); accB += uphi(u4);
      accA += uplo(u5); accB += uphi(u5);
      accA += uplo(u6); accB += uphi(u6);
      accA += uplo(u7); accB += uphi(u7);
      accA += uplo(u8); accB += uphi(u8);
      accA += uplo(u9); accB += uphi(u9);
      accA += uplo(ua); accB += uphi(ua);
      accA += uplo(ub); accB += uphi(ub);
    }
    for (int i = 0; i < oc; ++i) {  // cold fallback path
      int df = ovf[2 * i + 1];
      if ((df & 0x1FFFF) == n) {
        uint4 u = hw4[(size_t)ovf[2 * i] * 8 + li];
        accA += uplo(u);
        accB += uphi(u);
        c += ((df >> 30) & 1) ^ 1;
      }
    }
    if (n < N_NODES) {
      float inv = 1.f / (float)max(c, 1);
      float* op = out + (size_t)n * 64 + li * 8;
      float4 c0 = *reinterpret_cast<float4*>(op);
      float4 c1 = *reinterpret_cast<float4*>(op + 4);
      c0.x += accA.x * inv;
      c0.y += accA.y * inv;
      c0.z += accA.z * inv;
      c0.w += accA.w * inv;
      c1.x += accB.x * inv;
      c1.y += accB.y * inv;
      c1.z += accB.z * inv;
      c1.w += accB.w * inv;
      *reinterpret_cast<float4*>(op) = c0;
      *reinterpret_cast<float4*>(op + 4) = c1;
    }
  }
}

extern "C" void kernel_launch(void* const* d_in, const int* in_sizes, int n_in,
                              void* d_out, int out_size, void* d_ws,
                              size_t ws_size, hipStream_t stream) {
  const float* feat = (const float*)d_in[0];
  const int* src = (const int*)d_in[1];
  const int* dst = (const int*)d_in[2];
  const float* Ws0 = (const float*)d_in[3];
  const float* Wn0 = (const float*)d_in[4];
  const float* b0 = (const float*)d_in[5];
  const float* Ws1 = (const float*)d_in[6];
  const float* Wn1 = (const float*)d_in[7];
  const float* b1 = (const float*)d_in[8];
  char* ws = (char*)d_ws;

  // Workspace (72.2 MB <= 77.2 MB proven):
  //   coarse  @ 0          : 25,600,000  (coarse binbuf; k_pb/k_fb only)
  //   ovf_cnt @ 25,600,000 :         64
  //   gcursor @ 25,600,064 :      6,272  (1568 fine cursors, dense)
  //   ccur    @ 25,606,336 :        448  (98 coarse cursors, dense)
  //   ovf     @ 25,606,784 :     65,536
  //   binbuf  @ 25,672,320 :  8,002,560  (1563 x 1280 packed edges)
  //   feat_bf @ 33,674,880 : 25,600,256  (bf16 + zero row)
  //   hw      @ 59,275,136 : 12,800,128  (bf16 h@Wn1 + zero row)
  //   wp0     @ 72,075,264 :     65,536
  //   wp1     @ 72,140,800 :     32,768
  uint* coarse = (uint*)(ws);
  int* ovf_cnt = (int*)(ws + 25600000);
  uint* gcursor = (uint*)(ws + 25600064);
  uint* ccur = (uint*)(ws + 25606336);
  int* ovf = (int*)(ws + 25606784);
  uint* binbuf = (uint*)(ws + 25672320);
  ushort* fbf = (ushort*)(ws + 33674880);
  ushort* hw = (ushort*)(ws + 59275136);
  ushort* wp0 = (ushort*)(ws + 72075264);
  ushort* wp1 = (ushort*)(ws + 72140800);
  float* out = (float*)d_out;

  hipMemsetAsync(ws + 25600000, 0, 6784, stream);  // ovf_cnt+gcursor+ccur
  k_pb<<<GBLK + FBLK + 193, 256, 0, stream>>>(
      src, dst, feat, Ws0, Wn0, Ws1, Wn1, ccur, coarse, ovf_cnt, ovf,
      (uint*)fbf, (uint*)hw, wp0, wp1);
  k_fb<<<NCB * 16, 256, 0, stream>>>(coarse, ccur, gcursor, ovf_cnt, ovf,
                                     binbuf);
  k_ag<<<NBIN, 512, 0, stream>>>(fbf, (const uint4*)fbf, binbuf, gcursor,
                                 ovf_cnt, ovf, (const short8*)wp0,
                                 (const short8*)wp1, b0, b1, hw, out);
  k_agg1<<<NBIN, 256, 0, stream>>>((const uint4*)hw, binbuf, gcursor, ovf_cnt,
                                   ovf, out);
}

// Round 11
// 254.009 us; speedup vs baseline: 1.0409x; 1.0090x over previous
//
#include <hip/hip_runtime.h>

#define N_NODES 100000
#define N_EDGES 1600000
#define CAP 60         // per-node bucket capacity, mult. of 12 (Poisson(16): P(deg>60)~1e-16)
#define OVF_CAP 8192
#define GBLK 782       // ceil(100000/128): bin blocks (2048 edges)
#define NBIN 1563      // ceil(100000/64): fine bin = dst>>6; k_ag/k_agg1 grid
#define NCB 98         // ceil(100000/1024): coarse bin = dst>>10
#define CCAP 17408     // Poisson(16384) + 8 sigma
#define BINCAP2 1280   // Poisson(1024) + 8 sigma
#define CVTB 3125      // feat cvt blocks (grid-stride x4: 3125*1024 float4)
#define ZROW 100000    // zero row index (padding gathers)

typedef unsigned int uint;
typedef unsigned short ushort;
typedef __attribute__((ext_vector_type(8))) short short8;  // 8 bf16 (4 VGPRs)
typedef __attribute__((ext_vector_type(4))) float f32x4;   // 4 fp32

__device__ __forceinline__ ushort f2bf(float f) {
  uint x = __float_as_uint(f);
  x += 0x7fffu + ((x >> 16) & 1u);  // round-to-nearest-even
  return (ushort)(x >> 16);
}
__device__ __forceinline__ float bflo(uint u) {
  return __uint_as_float(u << 16);
}
__device__ __forceinline__ float bfhi(uint u) {
  return __uint_as_float(u & 0xffff0000u);
}
// low/high 4 floats of a uint4 (8 bf16)
__device__ __forceinline__ f32x4 uplo(uint4 u) {
  return (f32x4){bflo(u.x), bfhi(u.x), bflo(u.y), bfhi(u.y)};
}
__device__ __forceinline__ f32x4 uphi(uint4 u) {
  return (f32x4){bflo(u.z), bfhi(u.z), bflo(u.w), bfhi(u.w)};
}

// ---------------- fused: COARSE edge binning + feat cvt + weight packing ---
// Blocks [0,782): bin 2048 edges into 98 coarse (1024-node) segments.
// Edge loads int4-vectorized (8 consecutive edges/thread, 2+2 dwordx4);
// scalar-guarded tail in the last block only. Rank order inside a bin
// permutes vs scalar version (harmless: bucket contents order-independent).
// Blocks [782,3907): feat f32->bf16, grid-stride x4 (ILP + fewer blocks).
// Then 192 wp blocks + zero rows. Cursors DENSE (padding measured slower).
__global__ __launch_bounds__(256) void k_pb(
    const int* __restrict__ src, const int* __restrict__ dst,
    const float* __restrict__ feat, const float* __restrict__ Ws0,
    const float* __restrict__ Wn0, const float* __restrict__ Ws1,
    const float* __restrict__ Wn1, uint* __restrict__ ccur,
    uint* __restrict__ coarse, int* __restrict__ ovf_cnt,
    int* __restrict__ ovf, uint* __restrict__ fbfu, uint* __restrict__ hwu,
    ushort* __restrict__ wp0, ushort* __restrict__ wp1) {
  __shared__ uint hist[NCB];  // counts, then bases (overwritten in place)
  int b = blockIdx.x;
  int tid = threadIdx.x;
  if (b < GBLK) {
    if (tid < NCB) hist[tid] = 0;
    __syncthreads();
    int ebase = b * 2048 + tid * 8;
    uint val[8], bn[8], rk[8];
    int vld[8];
    if (ebase + 7 < N_EDGES) {  // fast path: 2+2 dwordx4 loads
      int4 s0 = reinterpret_cast<const int4*>(src)[ebase >> 2];
      int4 s1 = reinterpret_cast<const int4*>(src)[(ebase >> 2) + 1];
      int4 d0 = reinterpret_cast<const int4*>(dst)[ebase >> 2];
      int4 d1 = reinterpret_cast<const int4*>(dst)[(ebase >> 2) + 1];
      int ss[8] = {s0.x, s0.y, s0.z, s0.w, s1.x, s1.y, s1.z, s1.w};
      int dd[8] = {d0.x, d0.y, d0.z, d0.w, d1.x, d1.y, d1.z, d1.w};
#pragma unroll
      for (int it = 0; it < 8; ++it) {
        vld[it] = 1;
        uint d = (uint)dd[it];
        bn[it] = d >> 10;
        rk[it] = atomicAdd(&hist[bn[it]], 1u);
        val[it] = (uint)ss[it] | ((d & 1023u) << 17);  // 27 bits
      }
    } else {  // tail (last block only): scalar guarded
#pragma unroll
      for (int it = 0; it < 8; ++it) {
        int e = ebase + it;
        vld[it] = (e < N_EDGES);
        if (vld[it]) {
          uint s = (uint)src[e];
          uint d = (uint)dst[e];
          bn[it] = d >> 10;
          rk[it] = atomicAdd(&hist[bn[it]], 1u);
          val[it] = s | ((d & 1023u) << 17);
        }
      }
    }
    __syncthreads();
    if (tid < NCB) {
      uint h = hist[tid];
      hist[tid] = h ? atomicAdd(&ccur[tid], h) : 0u;  // count -> base
    }
    __syncthreads();
#pragma unroll
    for (int it = 0; it < 8; ++it) {
      if (!vld[it]) continue;
      uint p = hist[bn[it]] + rk[it];
      if (p < CCAP) {
        coarse[(size_t)bn[it] * CCAP + p] = val[it];
      } else {  // ~never: segment overflow -> ovf, NOT counted (bit30=0)
        int o = atomicAdd(ovf_cnt, 1);
        if (o < OVF_CAP) {
          ovf[2 * o] = (int)(val[it] & 0x1FFFFu);
          ovf[2 * o + 1] = (int)(bn[it] * 1024 + (val[it] >> 17));
        }
      }
    }
    return;
  }
  if (b < GBLK + CVTB) {  // feat conversion: 4 x (float4 in, uint2 out)
    int base = (b - GBLK) * 1024 + tid;
#pragma unroll
    for (int it = 0; it < 4; ++it) {
      int i = base + it * 256;
      float4 v = reinterpret_cast<const float4*>(feat)[i];
      uint2 o;
      o.x = (uint)f2bf(v.x) | ((uint)f2bf(v.y) << 16);
      o.y = (uint)f2bf(v.z) | ((uint)f2bf(v.w) << 16);
      reinterpret_cast<uint2*>(fbfu)[i] = o;
    }
    return;
  }
  int wb = b - GBLK - CVTB;
  if (wb >= 192) {  // zero padding rows fbf[100000], hw[100000]
    if (tid < 64) fbfu[ZROW * 64 + tid] = 0;
    else if (tid < 96) hwu[ZROW * 32 + (tid - 64)] = 0;
    return;
  }
  // B-frag layout (16x16x32 bf16): lane = 16q+c holds B[k=8q+j][n=16t+c].
  int idx = wb * 256 + tid;  // 49152 = 32768 + 16384
  if (idx < 32768) {
    int k = idx >> 7, n = idx & 127;
    float v = (k < 128) ? Ws0[k * 128 + n] : Wn0[(k - 128) * 128 + n];
    int s = k >> 5, q = (k >> 3) & 3, j = k & 7;
    int t = n >> 4, c = n & 15;
    wp0[(((s * 8 + t) * 64) + (q * 16 + c)) * 8 + j] = f2bf(v);
  } else {
    int i2 = idx - 32768;
    int k = i2 >> 7, n = i2 & 127;
    float v = (n < 64) ? Wn1[k * 64 + n] : Ws1[k * 64 + (n - 64)];
    int s = k >> 5, q = (k >> 3) & 3, j = k & 7;
    int t = n >> 4, c = n & 15;
    wp1[(((s * 8 + t) * 64) + (q * 16 + c)) * 8 + j] = f2bf(v);
  }
}

// ---------------- pass B: coarse -> fine binning ---------------------------
// 16 blocks per coarse bin; each scans 1/16 of the segment (coalesced reads)
// and scatters into the coarse bin's 16 fine (64-node) segments.
__global__ __launch_bounds__(256) void k_fb(
    const uint* __restrict__ coarse, const uint* __restrict__ ccur,
    uint* __restrict__ gcursor, int* __restrict__ ovf_cnt,
    int* __restrict__ ovf, uint* __restrict__ binbuf) {
  __shared__ uint hist[16];
  int blk = blockIdx.x;
  int tid = threadIdx.x;
  int cb = blk >> 4, q = blk & 15;
  if (tid < 16) hist[tid] = 0;
  __syncthreads();
  int ne = min((int)ccur[cb], CCAP);
  int lo = (q * ne) >> 4, hi = ((q + 1) * ne) >> 4;  // <= 1088 entries
  uint val[5], rk[5];
  int bnv[5], vld[5];
#pragma unroll
  for (int it = 0; it < 5; ++it) {
    int i = lo + it * 256 + tid;
    vld[it] = (i < hi);
    if (vld[it]) {
      uint v = coarse[(size_t)cb * CCAP + i];
      uint d10 = v >> 17;
      int f = (int)(d10 >> 6);  // 0..15
      rk[it] = atomicAdd(&hist[f], 1u);
      bnv[it] = f;
      val[it] = (v & 0x1FFFFu) | ((d10 & 63u) << 17);
    }
  }
  __syncthreads();
  if (tid < 16) {
    uint h = hist[tid];
    hist[tid] = h ? atomicAdd(&gcursor[cb * 16 + tid], h) : 0u;
  }
  __syncthreads();
#pragma unroll
  for (int it = 0; it < 5; ++it) {
    if (!vld[it]) continue;
    uint p = hist[bnv[it]] + rk[it];
    int fine = cb * 16 + bnv[it];
    if (p < BINCAP2) {
      binbuf[(size_t)fine * BINCAP2 + p] = val[it];
    } else {  // ~never: fine overflow -> ovf, NOT counted (bit30=0)
      int o = atomicAdd(ovf_cnt, 1);
      if (o < OVF_CAP) {
        ovf[2 * o] = (int)(val[it] & 0x1FFFFu);
        ovf[2 * o + 1] = fine * 64 + (int)(val[it] >> 17);
      }
    }
  }
}

// ---------------- FUSED agg0 + gemm0 + gemm1: 512 threads, 64 rows ---------
// Block bb owns nodes [bb*64, bb*64+64) = fine bin bb.
// A: bucket-scan binbuf into lbkt (aliases htile; ZROW-prefilled).
// B: 12-deep gather from fbf -> mean -> bf16 -> aggt LDS (XOR-swizzled).
// C: GEMM-0 h = relu([fbf | aggt] @ Wp0 + b0) -> htile (lbkt region, dead).
// D: GEMM-1 [hw | out] = htile @ Wp1.
// 64-row blocks: LDS 32KB -> 4 resident blocks/CU; independently phased
// blocks overlap gather-fetch with GEMM-MFMA (R10: 86.4us, 3.28 TB/s,
// FETCH 207.9MB = traffic floor; 92% of 3.57 TB/s path ceiling).
__global__ __launch_bounds__(512, 8) void k_ag(
    const ushort* __restrict__ fbf, const uint4* __restrict__ fbf4,
    const uint* __restrict__ binbuf, const uint* __restrict__ gcursor,
    int* __restrict__ ovf_cnt, int* __restrict__ ovf,
    const short8* __restrict__ wp0f, const short8* __restrict__ wp1f,
    const float* __restrict__ b0, const float* __restrict__ b1,
    ushort* __restrict__ hw, float* __restrict__ out) {
  __shared__ __attribute__((aligned(16))) ushort aggt[64 * 128];   // 16KB
  __shared__ __attribute__((aligned(16))) ushort htile[64 * 128];  // 16KB
  int* lbkt = (int*)htile;                  // [64*CAP] = 15360B
  uint* lcnt = (uint*)(htile + 7680);       // 256B @ byte 15360
  int bb = blockIdx.x;
  int tid = threadIdx.x;
  if (tid < 64) lcnt[tid] = 0;
  for (int i = tid; i < 64 * CAP; i += 512) lbkt[i] = ZROW;
  __syncthreads();
  int ne = min((int)gcursor[bb], BINCAP2);
  for (int i = tid; i < ne; i += 512) {
    uint v = binbuf[(size_t)bb * BINCAP2 + i];
    int ldl = (int)(v >> 17);
    uint pos = atomicAdd(&lcnt[ldl], 1u);
    if (pos < CAP) {
      lbkt[ldl * CAP + pos] = (int)(v & 0x1FFFFu);
    } else {  // ~never: bucket spill -> ovf, already counted (bit30=1)
      int o = atomicAdd(ovf_cnt, 1);
      if (o < OVF_CAP) {
        ovf[2 * o] = (int)(v & 0x1FFFFu);
        ovf[2 * o + 1] = (bb * 64 + ldl) | (1 << 30);
      }
    }
  }
  __syncthreads();
  {  // gather: 2 passes x (32 nodes x 16 lanes)
    int g16 = tid >> 4, li = tid & 15;
    const int4* lb4 = reinterpret_cast<const int4*>(lbkt);
    int oc = min(*ovf_cnt, OVF_CAP);
#pragma unroll
    for (int p = 0; p < 2; ++p) {
      int nl = p * 32 + g16;
      int n = bb * 64 + nl;
      int c = (int)lcnt[nl];
      int kb = min(c, CAP);
      f32x4 accA = (f32x4){0.f, 0.f, 0.f, 0.f};
      f32x4 accB = (f32x4){0.f, 0.f, 0.f, 0.f};
      for (int j = 0; j < kb; j += 12) {
        int4 ia = lb4[nl * 15 + (j >> 2)];
        int4 ib = lb4[nl * 15 + (j >> 2) + 1];
        int4 ic = lb4[nl * 15 + (j >> 2) + 2];
        uint4 u0 = fbf4[(size_t)ia.x * 16 + li];
        uint4 u1 = fbf4[(size_t)ia.y * 16 + li];
        uint4 u2 = fbf4[(size_t)ia.z * 16 + li];
        uint4 u3 = fbf4[(size_t)ia.w * 16 + li];
        uint4 u4 = fbf4[(size_t)ib.x * 16 + li];
        uint4 u5 = fbf4[(size_t)ib.y * 16 + li];
        uint4 u6 = fbf4[(size_t)ib.z * 16 + li];
        uint4 u7 = fbf4[(size_t)ib.w * 16 + li];
        uint4 u8 = fbf4[(size_t)ic.x * 16 + li];
        uint4 u9 = fbf4[(size_t)ic.y * 16 + li];
        uint4 ua = fbf4[(size_t)ic.z * 16 + li];
        uint4 ub = fbf4[(size_t)ic.w * 16 + li];
        accA += uplo(u0); accB += uphi(u0);
        accA += uplo(u1); accB += uphi(u1);
        accA += uplo(u2); accB += uphi(u2);
        accA += uplo(u3); accB += uphi(u3);
        accA += uplo(u4); accB += uphi(u4);
        accA += uplo(u5); accB += uphi(u5);
        accA += uplo(u6); accB += uphi(u6);
        accA += uplo(u7); accB += uphi(u7);
        accA += uplo(u8); accB += uphi(u8);
        accA += uplo(u9); accB += uphi(u9);
        accA += uplo(ua); accB += uphi(ua);
        accA += uplo(ub); accB += uphi(ub);
      }
      for (int i = 0; i < oc; ++i) {  // cold fallback path
        int df = ovf[2 * i + 1];
        if ((df & 0x1FFFF) == n) {
          uint4 u = fbf4[(size_t)ovf[2 * i] * 16 + li];
          accA += uplo(u);
          accB += uphi(u);
          c += ((df >> 30) & 1) ^ 1;
        }
      }
      float inv = 1.f / (float)max(c, 1);
      accA *= inv;
      accB *= inv;
      uint4 o;
      o.x = (uint)f2bf(accA.x) | ((uint)f2bf(accA.y) << 16);
      o.y = (uint)f2bf(accA.z) | ((uint)f2bf(accA.w) << 16);
      o.z = (uint)f2bf(accB.x) | ((uint)f2bf(accB.y) << 16);
      o.w = (uint)f2bf(accB.z) | ((uint)f2bf(accB.w) << 16);
      // swizzled store: cols li*8..li*8+7 of row nl (16B-aligned chunk)
      *reinterpret_cast<uint4*>(&aggt[nl * 128 + ((li * 8) ^ ((nl & 15) * 8))]) = o;
    }
  }
  __syncthreads();  // lbkt dead; htile region reusable

  int lane = tid & 63, w = tid >> 6;  // 8 waves
  int quad = lane >> 4, lm = lane & 15;
  int wr = w >> 2, wc = w & 3;  // wave tile: rows wr*32..+32, cols wc*32..+32
  int rl0 = wr * 32;
  f32x4 acc[2][2];
#pragma unroll
  for (int rt = 0; rt < 2; ++rt)
#pragma unroll
    for (int ct = 0; ct < 2; ++ct) acc[rt][ct] = (f32x4){0.f, 0.f, 0.f, 0.f};
  short8 az = {0, 0, 0, 0, 0, 0, 0, 0};

#pragma unroll
  for (int s = 0; s < 8; ++s) {  // GEMM-0: K=256 over [fbf | aggt]
    int koff = (s & 3) * 32 + quad * 8;
    short8 a[2];
    if (s < 4) {
#pragma unroll
      for (int rt = 0; rt < 2; ++rt) {
        int row = bb * 64 + rl0 + rt * 16 + lm;
        a[rt] = (row < N_NODES)
                    ? *reinterpret_cast<const short8*>(fbf + (size_t)row * 128 + koff)
                    : az;
      }
    } else {
#pragma unroll
      for (int rt = 0; rt < 2; ++rt) {
        int r = rl0 + rt * 16 + lm;
        a[rt] = *reinterpret_cast<const short8*>(
            &aggt[r * 128 + (koff ^ ((r & 15) * 8))]);
      }
    }
#pragma unroll
    for (int ct = 0; ct < 2; ++ct) {
      short8 b = wp0f[(s * 8 + wc * 2 + ct) * 64 + lane];
#pragma unroll
      for (int rt = 0; rt < 2; ++rt)
        acc[rt][ct] =
            __builtin_amdgcn_mfma_f32_16x16x32_bf16(a[rt], b, acc[rt][ct], 0, 0, 0);
    }
  }

  {  // epilogue 0 -> htile (bias + relu + bf16); tail rows zeroed
    float bv[2];
#pragma unroll
    for (int ct = 0; ct < 2; ++ct) bv[ct] = b0[(wc * 2 + ct) * 16 + lm];
#pragma unroll
    for (int rt = 0; rt < 2; ++rt)
#pragma unroll
      for (int ct = 0; ct < 2; ++ct)
#pragma unroll
        for (int i = 0; i < 4; ++i) {
          int r = rl0 + rt * 16 + quad * 4 + i;
          float v = (bb * 64 + r < N_NODES)
                        ? fmaxf(acc[rt][ct][i] + bv[ct], 0.f)
                        : 0.f;
          int col = (wc * 2 + ct) * 16 + lm;
          htile[r * 128 + (col ^ ((r & 15) * 8))] = f2bf(v);
        }
  }
  __syncthreads();

#pragma unroll
  for (int rt = 0; rt < 2; ++rt)
#pragma unroll
    for (int ct = 0; ct < 2; ++ct) acc[rt][ct] = (f32x4){0.f, 0.f, 0.f, 0.f};

#pragma unroll
  for (int s = 0; s < 4; ++s) {  // GEMM-1: K=128 from htile
    int koff = s * 32 + quad * 8;
    short8 a[2];
#pragma unroll
    for (int rt = 0; rt < 2; ++rt) {
      int r = rl0 + rt * 16 + lm;
      a[rt] = *reinterpret_cast<const short8*>(
          &htile[r * 128 + (koff ^ ((r & 15) * 8))]);
    }
#pragma unroll
    for (int ct = 0; ct < 2; ++ct) {
      short8 b = wp1f[(s * 8 + wc * 2 + ct) * 64 + lane];
#pragma unroll
      for (int rt = 0; rt < 2; ++rt)
        acc[rt][ct] =
            __builtin_amdgcn_mfma_f32_16x16x32_bf16(a[rt], b, acc[rt][ct], 0, 0, 0);
    }
  }

  if (wc < 2) {  // cols 0..63 -> hw = h@Wn1 (bf16)
#pragma unroll
    for (int rt = 0; rt < 2; ++rt)
#pragma unroll
      for (int ct = 0; ct < 2; ++ct)
#pragma unroll
        for (int i = 0; i < 4; ++i) {
          int row = bb * 64 + rl0 + rt * 16 + quad * 4 + i;
          if (row < N_NODES)
            hw[(size_t)row * 64 + (wc * 2 + ct) * 16 + lm] = f2bf(acc[rt][ct][i]);
        }
  } else {  // cols 64..127 -> out = h@Ws1 + b1 (f32)
    float bv[2];
#pragma unroll
    for (int ct = 0; ct < 2; ++ct) bv[ct] = b1[((wc - 2) * 2 + ct) * 16 + lm];
#pragma unroll
    for (int rt = 0; rt < 2; ++rt)
#pragma unroll
      for (int ct = 0; ct < 2; ++ct)
#pragma unroll
        for (int i = 0; i < 4; ++i) {
          int row = bb * 64 + rl0 + rt * 16 + quad * 4 + i;
          if (row < N_NODES)
            out[(size_t)row * 64 + ((wc - 2) * 2 + ct) * 16 + lm] =
                acc[rt][ct][i] + bv[ct];
        }
  }
}

// ---------------- layer-1 aggregation (LDS bucket): 64 nodes/block ---------
// R8 structure (best measured): 256 threads, 8 lanes per node, 12-deep.
__global__ __launch_bounds__(256) void k_agg1(
    const uint4* __restrict__ hw4, const uint* __restrict__ binbuf,
    const uint* __restrict__ gcursor, int* __restrict__ ovf_cnt,
    int* __restrict__ ovf, float* __restrict__ out) {
  __shared__ __attribute__((aligned(16))) int lbkt[64 * CAP];
  __shared__ uint lcnt[64];
  int bb = blockIdx.x;
  int tid = threadIdx.x;
  if (tid < 64) lcnt[tid] = 0;
#pragma unroll
  for (int i = tid; i < 64 * CAP; i += 256) lbkt[i] = ZROW;
  __syncthreads();
  int ne = min((int)gcursor[bb], BINCAP2);
  for (int i = tid; i < ne; i += 256) {
    uint v = binbuf[(size_t)bb * BINCAP2 + i];
    int ldl = (int)(v >> 17);
    uint pos = atomicAdd(&lcnt[ldl], 1u);
    if (pos < CAP) lbkt[ldl * CAP + pos] = (int)(v & 0x1FFFFu);
    // bucket spill already recorded in ovf by k_ag's pass (bit30=1)
  }
  __syncthreads();
  int g = tid >> 3, li = tid & 7;
  const int4* lb4 = reinterpret_cast<const int4*>(lbkt);
  int oc = min(*ovf_cnt, OVF_CAP);
#pragma unroll
  for (int p = 0; p < 2; ++p) {
    int nl = p * 32 + g;
    int n = bb * 64 + nl;
    int c = (int)lcnt[nl];
    int kb = min(c, CAP);
    f32x4 accA = (f32x4){0.f, 0.f, 0.f, 0.f};
    f32x4 accB = (f32x4){0.f, 0.f, 0.f, 0.f};
    for (int j = 0; j < kb; j += 12) {
      int4 ia = lb4[nl * 15 + (j >> 2)];
      int4 ib = lb4[nl * 15 + (j >> 2) + 1];
      int4 ic = lb4[nl * 15 + (j >> 2) + 2];
      uint4 u0 = hw4[(size_t)ia.x * 8 + li];
      uint4 u1 = hw4[(size_t)ia.y * 8 + li];
      uint4 u2 = hw4[(size_t)ia.z * 8 + li];
      uint4 u3 = hw4[(size_t)ia.w * 8 + li];
      uint4 u4 = hw4[(size_t)ib.x * 8 + li];
      uint4 u5 = hw4[(size_t)ib.y * 8 + li];
      uint4 u6 = hw4[(size_t)ib.z * 8 + li];
      uint4 u7 = hw4[(size_t)ib.w * 8 + li];
      uint4 u8 = hw4[(size_t)ic.x * 8 + li];
      uint4 u9 = hw4[(size_t)ic.y * 8 + li];
      uint4 ua = hw4[(size_t)ic.z * 8 + li];
      uint4 ub = hw4[(size_t)ic.w * 8 + li];
      accA += uplo(u0); accB += uphi(u0);
      accA += uplo(u1); accB += uphi(u1);
      accA += uplo(u2); accB += uphi(u2);
      accA += uplo(u3); accB += uphi(u3);
      accA += uplo(u4); accB += uphi(u4);
      accA += uplo(u5); accB += uphi(u5);
      accA += uplo(u6); accB += uphi(u6);
      accA += uplo(u7); accB += uphi(u7);
      accA += uplo(u8); accB += uphi(u8);
      accA += uplo(u9); accB += uphi(u9);
      accA += uplo(ua); accB += uphi(ua);
      accA += uplo(ub); accB += uphi(ub);
    }
    for (int i = 0; i < oc; ++i) {  // cold fallback path
      int df = ovf[2 * i + 1];
      if ((df & 0x1FFFF) == n) {
        uint4 u = hw4[(size_t)ovf[2 * i] * 8 + li];
        accA += uplo(u);
        accB += uphi(u);
        c += ((df >> 30) & 1) ^ 1;
      }
    }
    if (n < N_NODES) {
      float inv = 1.f / (float)max(c, 1);
      float* op = out + (size_t)n * 64 + li * 8;
      float4 c0 = *reinterpret_cast<float4*>(op);
      float4 c1 = *reinterpret_cast<float4*>(op + 4);
      c0.x += accA.x * inv;
      c0.y += accA.y * inv;
      c0.z += accA.z * inv;
      c0.w += accA.w * inv;
      c1.x += accB.x * inv;
      c1.y += accB.y * inv;
      c1.z += accB.z * inv;
      c1.w += accB.w * inv;
      *reinterpret_cast<float4*>(op) = c0;
      *reinterpret_cast<float4*>(op + 4) = c1;
    }
  }
}

extern "C" void kernel_launch(void* const* d_in, const int* in_sizes, int n_in,
                              void* d_out, int out_size, void* d_ws,
                              size_t ws_size, hipStream_t stream) {
  const float* feat = (const float*)d_in[0];
  const int* src = (const int*)d_in[1];
  const int* dst = (const int*)d_in[2];
  const float* Ws0 = (const float*)d_in[3];
  const float* Wn0 = (const float*)d_in[4];
  const float* b0 = (const float*)d_in[5];
  const float* Ws1 = (const float*)d_in[6];
  const float* Wn1 = (const float*)d_in[7];
  const float* b1 = (const float*)d_in[8];
  char* ws = (char*)d_ws;

  // Workspace (72.2 MB <= 77.2 MB proven):
  //   coarse  @ 0          : 25,600,000  (coarse binbuf; k_pb/k_fb only)
  //   ovf_cnt @ 25,600,000 :         64
  //   gcursor @ 25,600,064 :      6,272  (1568 fine cursors, dense)
  //   ccur    @ 25,606,336 :        448  (98 coarse cursors, dense)
  //   ovf     @ 25,606,784 :     65,536
  //   binbuf  @ 25,672,320 :  8,002,560  (1563 x 1280 packed edges)
  //   feat_bf @ 33,674,880 : 25,600,256  (bf16 + zero row)
  //   hw      @ 59,275,136 : 12,800,128  (bf16 h@Wn1 + zero row)
  //   wp0     @ 72,075,264 :     65,536
  //   wp1     @ 72,140,800 :     32,768
  uint* coarse = (uint*)(ws);
  int* ovf_cnt = (int*)(ws + 25600000);
  uint* gcursor = (uint*)(ws + 25600064);
  uint* ccur = (uint*)(ws + 25606336);
  int* ovf = (int*)(ws + 25606784);
  uint* binbuf = (uint*)(ws + 25672320);
  ushort* fbf = (ushort*)(ws + 33674880);
  ushort* hw = (ushort*)(ws + 59275136);
  ushort* wp0 = (ushort*)(ws + 72075264);
  ushort* wp1 = (ushort*)(ws + 72140800);
  float* out = (float*)d_out;

  hipMemsetAsync(ws + 25600000, 0, 6784, stream);  // ovf_cnt+gcursor+ccur
  k_pb<<<GBLK + CVTB + 193, 256, 0, stream>>>(
      src, dst, feat, Ws0, Wn0, Ws1, Wn1, ccur, coarse, ovf_cnt, ovf,
      (uint*)fbf, (uint*)hw, wp0, wp1);
  k_fb<<<NCB * 16, 256, 0, stream>>>(coarse, ccur, gcursor, ovf_cnt, ovf,
                                     binbuf);
  k_ag<<<NBIN, 512, 0, stream>>>(fbf, (const uint4*)fbf, binbuf, gcursor,
                                 ovf_cnt, ovf, (const short8*)wp0,
                                 (const short8*)wp1, b0, b1, hw, out);
  k_agg1<<<NBIN, 256, 0, stream>>>((const uint4*)hw, binbuf, gcursor, ovf_cnt,
                                   ovf, out);
}